// Round 7
// baseline (603.763 us; speedup 1.0000x reference)
//
#include <hip/hip_runtime.h>
#include <hip/hip_fp16.h>
#include <cstdint>
#include <cstddef>
#include <math.h>

// Problem constants (match reference: B,C,N,K = 16,64,2048,20)
#define BB 16
#define CC 64
#define NN 2048
#define KK 20
#define K2 14   // ceil(20*2/3)
#define TQ 8    // queries per block in knn kernel (one per wave)
#define NC 26   // candidate count (margin over K=20 for approx->fp64 rank safety)
#define SPH 2052 // fp16 pd row stride (halves)

// native clang vector types (HIP float2/float4 are classes; asm needs these)
typedef float nfloat4 __attribute__((ext_vector_type(4)));
typedef float nf2 __attribute__((ext_vector_type(2)));

// ---------------------------------------------------------------------------
// prep: xt[b][n][c] = x[b][c][n]  (fp32, 256B rows), plus norms in fp64+fp32.
// ---------------------------------------------------------------------------
__global__ __launch_bounds__(256) void prep_kernel(const float* __restrict__ x,
                                                   float* __restrict__ xt,
                                                   float* __restrict__ xxf,
                                                   double* __restrict__ xxd) {
    __shared__ float s_t[64][65];
    int b = blockIdx.x >> 5;
    int n0 = (blockIdx.x & 31) * 64;
    const float* xb = x + (size_t)b * CC * NN;
    int tid = threadIdx.x;
    int cq = tid >> 6;
    int nl = tid & 63;

#pragma unroll
    for (int r = 0; r < 16; ++r) {
        int c = r * 4 + cq;
        s_t[c][nl] = xb[c * NN + n0 + nl];
    }
    __syncthreads();

#pragma unroll
    for (int r = 0; r < 16; ++r) {
        int n = r * 4 + cq;
        xt[((size_t)b * NN + n0 + n) * CC + nl] = s_t[nl][n];
    }

    if (tid < 64) {
        double s = 0.0;
#pragma unroll
        for (int c = 0; c < CC; ++c) {
            double v = (double)s_t[c][tid];
            s += v * v;
        }
        xxd[b * NN + n0 + tid] = s;
        xxf[b * NN + n0 + tid] = (float)s;
    }
}

// ---------------------------------------------------------------------------
// knn v8: v7 structure (fp16 pd LDS, 41KB, 3 blocks/CU) + packed-fp32 fill.
// Fill inner loop: 16 x v_pk_fma_f32 per c-iter (was 32 scalar v_fma_f32).
//   Queries packed as float2 pairs straight from the ds_read_b128 of s_q;
//   x-scalar broadcast via VOP3P op_sel (no splat movs). Per-accumulator
//   FMA chain order identical to scalar version -> bit-identical pd.
// Phase 2: per-wave threshold selection (unchanged from 602us version).
// Phase 3: fp64 refine, candidate rows direct from global (L2-hot).
// ---------------------------------------------------------------------------
__global__ __launch_bounds__(512, 6) void knn_kernel(const float* __restrict__ x,
                                                     const float* __restrict__ xt,
                                                     const float* __restrict__ xxf,
                                                     const double* __restrict__ xxd,
                                                     int* __restrict__ idx_ws,
                                                     float* __restrict__ idx_out) {
    __shared__ __half s_pd[TQ][SPH];               // 32.8 KiB fp16 pd rows
    __shared__ __align__(16) float s_q[CC][TQ];    // 2 KiB, [c][q] for fill
    __shared__ __align__(16) float s_qT[TQ][CC];   // 2 KiB, [q][c] for phase 3
    __shared__ float s_sv[TQ][64];                 // survivor values
    __shared__ int   s_si[TQ][64];                 // survivor indices

    int tid = threadIdx.x;
    int b = blockIdx.x >> 8;                       // NN/TQ = 256 blocks/batch
    int n0 = (blockIdx.x & 255) * TQ;
    const float* xb = x + (size_t)b * CC * NN;

    {
        int c = tid >> 3, qq = tid & 7;
        float qv = xb[c * NN + n0 + qq];
        s_q[c][qq] = qv;
        s_qT[qq][c] = qv;
    }
    __syncthreads();

    // ---- phase 1: fill (thread owns 4 consecutive m for all 8 queries) ----
    {
        float4 xa = *(const float4*)(xxf + b * NN + n0);
        float4 xc = *(const float4*)(xxf + b * NN + n0 + 4);
        float xxn[TQ] = {xa.x, xa.y, xa.z, xa.w, xc.x, xc.y, xc.z, xc.w};

        int m = tid * 4;
        nf2 acc[4][4];                             // [qpair][i]: .x=q even, .y=q odd
#pragma unroll
        for (int qp = 0; qp < 4; ++qp)
#pragma unroll
            for (int i = 0; i < 4; ++i) acc[qp][i] = (nf2){0.f, 0.f};

        for (int c = 0; c < CC; ++c) {
            float4 xv = *(const float4*)(xb + c * NN + m);
            nf2 x01 = {xv.x, xv.y};
            nf2 x23 = {xv.z, xv.w};
            float4 qa = *(const float4*)(&s_q[c][0]);
            float4 qb = *(const float4*)(&s_q[c][4]);
            nf2 q2[4] = {{qa.x, qa.y}, {qa.z, qa.w}, {qb.x, qb.y}, {qb.z, qb.w}};
#pragma unroll
            for (int qp = 0; qp < 4; ++qp) {
                // acc[qp][i] += q2[qp] * broadcast(x[i])
                asm("v_pk_fma_f32 %0, %1, %2, %0 op_sel:[0,0,0] op_sel_hi:[1,0,1]"
                    : "+v"(acc[qp][0]) : "v"(q2[qp]), "v"(x01));
                asm("v_pk_fma_f32 %0, %1, %2, %0 op_sel:[0,1,0] op_sel_hi:[1,1,1]"
                    : "+v"(acc[qp][1]) : "v"(q2[qp]), "v"(x01));
                asm("v_pk_fma_f32 %0, %1, %2, %0 op_sel:[0,0,0] op_sel_hi:[1,0,1]"
                    : "+v"(acc[qp][2]) : "v"(q2[qp]), "v"(x23));
                asm("v_pk_fma_f32 %0, %1, %2, %0 op_sel:[0,1,0] op_sel_hi:[1,1,1]"
                    : "+v"(acc[qp][3]) : "v"(q2[qp]), "v"(x23));
            }
        }
        float4 xm4 = *(const float4*)(xxf + b * NN + m);
        float xms[4] = {xm4.x, xm4.y, xm4.z, xm4.w};
#pragma unroll
        for (int qp = 0; qp < 4; ++qp) {
            int q0 = qp * 2, q1 = qp * 2 + 1;
            float p0[4], p1[4];
#pragma unroll
            for (int i = 0; i < 4; ++i) {
                p0[i] = (2.f * acc[qp][i].x - xxn[q0]) - xms[i];
                p1[i] = (2.f * acc[qp][i].y - xxn[q1]) - xms[i];
            }
            *(__half2*)(&s_pd[q0][m])     = __floats2half2_rn(p0[0], p0[1]);
            *(__half2*)(&s_pd[q0][m + 2]) = __floats2half2_rn(p0[2], p0[3]);
            *(__half2*)(&s_pd[q1][m])     = __floats2half2_rn(p1[0], p1[1]);
            *(__half2*)(&s_pd[q1][m + 2]) = __floats2half2_rn(p1[2], p1[3]);
        }
    }
    __syncthreads();

    // ---- phase 2: per-wave selection ----
    int q = tid >> 6;
    int lane = tid & 63;
    const __half* pd = &s_pd[q][0];

    float v[32];
#pragma unroll
    for (int r = 0; r < 32; ++r) v[r] = __half2float(pd[lane + (r << 6)]);

    float lmax = v[0]; int lr = 0;
#pragma unroll
    for (int r = 1; r < 32; ++r)
        if (v[r] > lmax) { lmax = v[r]; lr = r; }              // strict > : lowest idx

    // tau = 26th-largest lane-max (values-only 64-lane bitonic, descending)
    float sv = lmax;
#pragma unroll
    for (int k = 2; k <= 64; k <<= 1) {
#pragma unroll
        for (int j = k >> 1; j > 0; j >>= 1) {
            float o = __shfl_xor(sv, j);
            bool dird = ((lane & k) == 0);
            bool first = ((lane & j) == 0);
            sv = (first == dird) ? fmaxf(sv, o) : fminf(sv, o);
        }
    }
    float tau = __shfl(sv, 25);

    int cnt = 0;
#pragma unroll
    for (int r = 0; r < 32; ++r) cnt += (v[r] >= tau) ? 1 : 0;
    int incl = cnt;
#pragma unroll
    for (int off = 1; off < 64; off <<= 1) {
        int o = __shfl_up(incl, off);
        if (lane >= off) incl += o;
    }
    int S = __shfl(incl, 63);

    float fv = -INFINITY;
    int fi = 0x7fffffff;
    if (S <= 64) {
        int w = incl - cnt;
#pragma unroll
        for (int r = 0; r < 32; ++r) {
            if (v[r] >= tau) { s_sv[q][w] = v[r]; s_si[q][w] = lane + (r << 6); ++w; }
        }
        if (lane < S) { fv = s_sv[q][lane]; fi = s_si[q][lane]; }
    } else {
        // pathological (mass ties): exact iterative top-26 extraction
        for (int t = 0; t < NC; ++t) {
            float bv = lmax; int bi = lane + (lr << 6);
#pragma unroll
            for (int off = 32; off; off >>= 1) {
                float ov = __shfl_xor(bv, off);
                int oi = __shfl_xor(bi, off);
                if (ov > bv || (ov == bv && oi < bi)) { bv = ov; bi = oi; }
            }
            if (lane == t) { fv = bv; fi = bi; }
            if ((bi & 63) == lane) {
                int rsel = bi >> 6;
#pragma unroll
                for (int r = 0; r < 32; ++r) if (r == rsel) v[r] = -INFINITY;
                lmax = v[0]; lr = 0;
#pragma unroll
                for (int r = 1; r < 32; ++r)
                    if (v[r] > lmax) { lmax = v[r]; lr = r; }
            }
        }
    }

    // 64-lane bitonic sort of (fv desc, fi asc) -> lanes 0..25 = approx top-26
#pragma unroll
    for (int k = 2; k <= 64; k <<= 1) {
#pragma unroll
        for (int j = k >> 1; j > 0; j >>= 1) {
            float ov = __shfl_xor(fv, j);
            int oi = __shfl_xor(fi, j);
            bool dird = ((lane & k) == 0);
            bool first = ((lane & j) == 0);
            bool better = (fv > ov) || (fv == ov && fi < oi);
            if (better != (first == dird)) { fv = ov; fi = oi; }
        }
    }

    // ---- phase 3: fp64 refine (direct global candidate rows, L2-hot) ----
    int nq = n0 + q;
    double accd = 0.0;
    if (lane < NC) {
        const float* crow = xt + (size_t)b * NN * CC + (size_t)fi * CC;
        const float* qrow = &s_qT[q][0];
        double a0 = 0.0, a1 = 0.0, a2 = 0.0, a3 = 0.0;
#pragma unroll
        for (int j = 0; j < 16; ++j) {
            float4 cv = *(const float4*)(crow + j * 4);
            float4 qv = *(const float4*)(qrow + j * 4);   // LDS b128 broadcast
            a0 = fma((double)qv.x, (double)cv.x, a0);
            a1 = fma((double)qv.y, (double)cv.y, a1);
            a2 = fma((double)qv.z, (double)cv.z, a2);
            a3 = fma((double)qv.w, (double)cv.w, a3);
        }
        accd = (a0 + a1) + (a2 + a3);
    }

    double val = -INFINITY;
    int idxq = 0x7fffffff;
    if (lane < NC) {
        val = 2.0 * accd - xxd[b * NN + nq] - xxd[b * NN + fi];
        idxq = fi;
    }

    // 32-lane fp64 bitonic (val desc, idx asc)
#pragma unroll
    for (int k = 2; k <= 32; k <<= 1) {
#pragma unroll
        for (int j = k >> 1; j > 0; j >>= 1) {
            double ov = __shfl_xor(val, j, 32);
            int oi = __shfl_xor(idxq, j, 32);
            bool dird = ((lane & k) == 0);
            bool first = ((lane & j) == 0);
            bool better = (val > ov) || (val == ov && idxq < oi);
            if (better != (first == dird)) { val = ov; idxq = oi; }
        }
    }

    if (lane < KK) {
        size_t obase = ((size_t)b * NN + nq) * KK;
        idx_ws[obase + lane] = idxq;
        idx_out[obase + lane] = (float)(idxq + b * NN);
    }
}

// ---------------------------------------------------------------------------
// x1: mean of top-14 of 20 gathered neighbor values, written channel-major
// as x1t[b][c][n]. (sum20 - six minima)/14, order-independent.
// ---------------------------------------------------------------------------
__global__ __launch_bounds__(256) void x1_kernel(const float* __restrict__ xt,
                                                 const int* __restrict__ idx_ws,
                                                 float* __restrict__ x1t) {
    __shared__ int s_idx[16][KK];
    __shared__ float s_out[64][17];
    int tid = threadIdx.x;
    int b = blockIdx.x >> 7;
    int n0 = (blockIdx.x & 127) * 16;
    const float* xtb = xt + (size_t)b * NN * CC;

    for (int i = tid; i < 16 * KK; i += 256)
        s_idx[i / KK][i % KK] = idx_ws[((size_t)b * NN + n0) * KK + i];
    __syncthreads();

    int pl = tid >> 6, c = tid & 63;
#pragma unroll
    for (int it = 0; it < 4; ++it) {
        int nl = it * 4 + pl;
        float vals[KK];
        float sum = 0.f;
#pragma unroll
        for (int j = 0; j < KK; ++j) {
            vals[j] = xtb[(size_t)s_idx[nl][j] * CC + c];
            sum += vals[j];
        }
#pragma unroll
        for (int t = 0; t < KK - K2; ++t) {
            float worst = INFINITY;
            int wj = 0;
#pragma unroll
            for (int j = 0; j < KK; ++j)
                if (vals[j] < worst) { worst = vals[j]; wj = j; }
            sum -= worst;
            vals[wj] = INFINITY;
        }
        s_out[c][nl] = sum / (float)K2;
    }
    __syncthreads();

    int cw = tid >> 2, nw = (tid & 3) * 4;
    float4 v = make_float4(s_out[cw][nw], s_out[cw][nw + 1],
                           s_out[cw][nw + 2], s_out[cw][nw + 3]);
    *(float4*)(&x1t[((size_t)b * CC + cw) * NN + n0 + nw]) = v;
}

// ---------------------------------------------------------------------------
// feat: float4-vectorized. feature[b,ch,n,j]:
//   ch <  64: x1t[b,ch,idx[b,n,j]] - x[b,ch,n]
//   ch >= 64: x[b,ch-64,n]
// Write-only 335 MB output -> non-temporal stores.
// ---------------------------------------------------------------------------
__global__ __launch_bounds__(256) void feat_kernel(const float* __restrict__ x,
                                                   const float* __restrict__ x1t,
                                                   const int* __restrict__ idx_ws,
                                                   float* __restrict__ out) {
    int bc = blockIdx.x;
    int b = bc >> 7, ch = bc & 127;
    const float* xb = x + (size_t)b * CC * NN;
    float* o = out + (size_t)bc * NN * KK;
    const int* idxb = idx_ws + (size_t)b * NN * KK;

    if (ch < CC) {
        const float* row = x1t + ((size_t)b * CC + ch) * NN;
        const float* xr = xb + ch * NN;
        for (int it = 0; it < 40; ++it) {
            unsigned e = (it * 256 + threadIdx.x) * 4;
            int4 id4 = *(const int4*)(idxb + e);
            nfloat4 o4;
            o4.x = row[id4.x] - xr[(e    ) / KK];
            o4.y = row[id4.y] - xr[(e + 1) / KK];
            o4.z = row[id4.z] - xr[(e + 2) / KK];
            o4.w = row[id4.w] - xr[(e + 3) / KK];
            __builtin_nontemporal_store(o4, (nfloat4*)(o + e));
        }
    } else {
        const float* xr = xb + (ch - CC) * NN;
        for (int it = 0; it < 40; ++it) {
            unsigned e = (it * 256 + threadIdx.x) * 4;
            nfloat4 o4;
            o4.x = xr[(e    ) / KK];
            o4.y = xr[(e + 1) / KK];
            o4.z = xr[(e + 2) / KK];
            o4.w = xr[(e + 3) / KK];
            __builtin_nontemporal_store(o4, (nfloat4*)(o + e));
        }
    }
}

// ---------------------------------------------------------------------------
extern "C" void kernel_launch(void* const* d_in, const int* in_sizes, int n_in,
                              void* d_out, int out_size, void* d_ws, size_t ws_size,
                              hipStream_t stream) {
    const float* x = (const float*)d_in[0];   // (B, C, N) fp32
    float* out = (float*)d_out;

    char* ws = (char*)d_ws;
    float* xt   = (float*)ws;                                   // B*N*C
    float* x1t  = (float*)(ws + (size_t)8388608);               // B*C*N
    double* xxd = (double*)(ws + (size_t)16777216);             // B*N
    float* xxf  = (float*)(ws + (size_t)17039360);              // B*N
    int* idx_ws = (int*)(ws + (size_t)17170432);                // B*N*K

    float* idx_out = out + (size_t)BB * 2 * CC * NN * KK;       // idx_flat tail

    prep_kernel<<<BB * (NN / 64), 256, 0, stream>>>(x, xt, xxf, xxd);
    knn_kernel<<<BB * (NN / TQ), 512, 0, stream>>>(x, xt, xxf, xxd, idx_ws, idx_out);
    x1_kernel<<<BB * (NN / 16), 256, 0, stream>>>(xt, idx_ws, x1t);
    feat_kernel<<<BB * 2 * CC, 256, 0, stream>>>(x, x1t, idx_ws, out);
}

// Round 8
// 579.818 us; speedup vs baseline: 1.0413x; 1.0413x over previous
//
#include <hip/hip_runtime.h>
#include <hip/hip_fp16.h>
#include <cstdint>
#include <cstddef>
#include <math.h>

// Problem constants (match reference: B,C,N,K = 16,64,2048,20)
#define BB 16
#define CC 64
#define NN 2048
#define KK 20
#define K2 14   // ceil(20*2/3)
#define TQ 8    // queries per block in knn kernel (one per wave)
#define NC 26   // candidate count (margin over K=20 for approx->fp64 rank safety)
#define SPH 2052 // fp16 pd row stride (halves)

// native clang vector type for nontemporal builtin (HIP float4 is a class)
typedef float nfloat4 __attribute__((ext_vector_type(4)));

// ---------------------------------------------------------------------------
// prep: xt[b][n][c] = x[b][c][n]  (fp32, 256B rows), plus norms in fp64+fp32.
// ---------------------------------------------------------------------------
__global__ __launch_bounds__(256) void prep_kernel(const float* __restrict__ x,
                                                   float* __restrict__ xt,
                                                   float* __restrict__ xxf,
                                                   double* __restrict__ xxd) {
    __shared__ float s_t[64][65];
    int b = blockIdx.x >> 5;
    int n0 = (blockIdx.x & 31) * 64;
    const float* xb = x + (size_t)b * CC * NN;
    int tid = threadIdx.x;
    int cq = tid >> 6;
    int nl = tid & 63;

#pragma unroll
    for (int r = 0; r < 16; ++r) {
        int c = r * 4 + cq;
        s_t[c][nl] = xb[c * NN + n0 + nl];
    }
    __syncthreads();

#pragma unroll
    for (int r = 0; r < 16; ++r) {
        int n = r * 4 + cq;
        xt[((size_t)b * NN + n0 + n) * CC + nl] = s_t[nl][n];
    }

    if (tid < 64) {
        double s = 0.0;
#pragma unroll
        for (int c = 0; c < CC; ++c) {
            double v = (double)s_t[c][tid];
            s += v * v;
        }
        xxd[b * NN + n0 + tid] = s;
        xxf[b * NN + n0 + tid] = (float)s;
    }
}

// ---------------------------------------------------------------------------
// knn v9: v7 structure (fp16 pd, selection/refine identical) with the fill's
// query reads moved from LDS to the SCALAR path. The 8 q-values per c-iter
// sit contiguously at wave-uniform address xb + c*NN + n0 -> s_load_dwordx4
// through the constant cache; v_fmac takes the SGPR operand directly.
// This removes 128 ds_read_b128/thread (~82us/CU of LDS-pipe time, the
// dominant fill cost per v6/v7/v8 A/B evidence). s_q deleted: LDS 39KB ->
// 4 blocks/CU; launch_bounds(512,8) pins VGPR<=64 (v7/v8 fit 64 with more
// live state).
// ---------------------------------------------------------------------------
__global__ __launch_bounds__(512, 8) void knn_kernel(const float* __restrict__ x,
                                                     const float* __restrict__ xt,
                                                     const float* __restrict__ xxf,
                                                     const double* __restrict__ xxd,
                                                     int* __restrict__ idx_ws,
                                                     float* __restrict__ idx_out) {
    __shared__ __half s_pd[TQ][SPH];               // 32.8 KiB fp16 pd rows
    __shared__ __align__(16) float s_qT[TQ][CC];   // 2 KiB, [q][c] for phase 3
    __shared__ float s_sv[TQ][64];                 // survivor values
    __shared__ int   s_si[TQ][64];                 // survivor indices

    int tid = threadIdx.x;
    int b = blockIdx.x >> 8;                       // NN/TQ = 256 blocks/batch
    int n0 = (blockIdx.x & 255) * TQ;
    const float* xb = x + (size_t)b * CC * NN;

    {
        int c = tid >> 3, qq = tid & 7;
        s_qT[qq][c] = xb[c * NN + n0 + qq];
    }
    __syncthreads();

    // ---- phase 1: fill (thread owns 4 consecutive m for all 8 queries) ----
    {
        float4 xa = *(const float4*)(xxf + b * NN + n0);
        float4 xc = *(const float4*)(xxf + b * NN + n0 + 4);
        float xxn[TQ] = {xa.x, xa.y, xa.z, xa.w, xc.x, xc.y, xc.z, xc.w};

        int m = tid * 4;
        float acc[TQ][4];
#pragma unroll
        for (int q = 0; q < TQ; ++q)
#pragma unroll
            for (int i = 0; i < 4; ++i) acc[q][i] = 0.f;

        for (int c = 0; c < CC; ++c) {
            float4 xv = *(const float4*)(xb + c * NN + m);
            // wave-uniform address -> scalar loads (constant cache, no LDS)
            const float* qp = xb + c * NN + n0;
            float4 qa = *(const float4*)(qp);
            float4 qb = *(const float4*)(qp + 4);
            float xs[4] = {xv.x, xv.y, xv.z, xv.w};
            float qs[TQ] = {qa.x, qa.y, qa.z, qa.w, qb.x, qb.y, qb.z, qb.w};
#pragma unroll
            for (int q = 0; q < TQ; ++q)
#pragma unroll
                for (int i = 0; i < 4; ++i) acc[q][i] += qs[q] * xs[i];
        }
        float4 xm4 = *(const float4*)(xxf + b * NN + m);
        float xms[4] = {xm4.x, xm4.y, xm4.z, xm4.w};
#pragma unroll
        for (int q = 0; q < TQ; ++q) {
            float4 pdv;
            pdv.x = (2.f * acc[q][0] - xxn[q]) - xms[0];
            pdv.y = (2.f * acc[q][1] - xxn[q]) - xms[1];
            pdv.z = (2.f * acc[q][2] - xxn[q]) - xms[2];
            pdv.w = (2.f * acc[q][3] - xxn[q]) - xms[3];
            __half2 h01 = __floats2half2_rn(pdv.x, pdv.y);
            __half2 h23 = __floats2half2_rn(pdv.z, pdv.w);
            *(__half2*)(&s_pd[q][m]) = h01;
            *(__half2*)(&s_pd[q][m + 2]) = h23;
        }
    }
    __syncthreads();

    // ---- phase 2: per-wave selection ----
    int q = tid >> 6;
    int lane = tid & 63;
    const __half* pd = &s_pd[q][0];

    float v[32];
#pragma unroll
    for (int r = 0; r < 32; ++r) v[r] = __half2float(pd[lane + (r << 6)]);

    float lmax = v[0]; int lr = 0;
#pragma unroll
    for (int r = 1; r < 32; ++r)
        if (v[r] > lmax) { lmax = v[r]; lr = r; }              // strict > : lowest idx

    // tau = 26th-largest lane-max (values-only 64-lane bitonic, descending)
    float sv = lmax;
#pragma unroll
    for (int k = 2; k <= 64; k <<= 1) {
#pragma unroll
        for (int j = k >> 1; j > 0; j >>= 1) {
            float o = __shfl_xor(sv, j);
            bool dird = ((lane & k) == 0);
            bool first = ((lane & j) == 0);
            sv = (first == dird) ? fmaxf(sv, o) : fminf(sv, o);
        }
    }
    float tau = __shfl(sv, 25);

    int cnt = 0;
#pragma unroll
    for (int r = 0; r < 32; ++r) cnt += (v[r] >= tau) ? 1 : 0;
    int incl = cnt;
#pragma unroll
    for (int off = 1; off < 64; off <<= 1) {
        int o = __shfl_up(incl, off);
        if (lane >= off) incl += o;
    }
    int S = __shfl(incl, 63);

    float fv = -INFINITY;
    int fi = 0x7fffffff;
    if (S <= 64) {
        int w = incl - cnt;
#pragma unroll
        for (int r = 0; r < 32; ++r) {
            if (v[r] >= tau) { s_sv[q][w] = v[r]; s_si[q][w] = lane + (r << 6); ++w; }
        }
        if (lane < S) { fv = s_sv[q][lane]; fi = s_si[q][lane]; }
    } else {
        // pathological (mass ties): exact iterative top-26 extraction
        for (int t = 0; t < NC; ++t) {
            float bv = lmax; int bi = lane + (lr << 6);
#pragma unroll
            for (int off = 32; off; off >>= 1) {
                float ov = __shfl_xor(bv, off);
                int oi = __shfl_xor(bi, off);
                if (ov > bv || (ov == bv && oi < bi)) { bv = ov; bi = oi; }
            }
            if (lane == t) { fv = bv; fi = bi; }
            if ((bi & 63) == lane) {
                int rsel = bi >> 6;
#pragma unroll
                for (int r = 0; r < 32; ++r) if (r == rsel) v[r] = -INFINITY;
                lmax = v[0]; lr = 0;
#pragma unroll
                for (int r = 1; r < 32; ++r)
                    if (v[r] > lmax) { lmax = v[r]; lr = r; }
            }
        }
    }

    // 64-lane bitonic sort of (fv desc, fi asc) -> lanes 0..25 = approx top-26
#pragma unroll
    for (int k = 2; k <= 64; k <<= 1) {
#pragma unroll
        for (int j = k >> 1; j > 0; j >>= 1) {
            float ov = __shfl_xor(fv, j);
            int oi = __shfl_xor(fi, j);
            bool dird = ((lane & k) == 0);
            bool first = ((lane & j) == 0);
            bool better = (fv > ov) || (fv == ov && fi < oi);
            if (better != (first == dird)) { fv = ov; fi = oi; }
        }
    }

    // ---- phase 3: fp64 refine (direct global candidate rows, L2-hot) ----
    int nq = n0 + q;
    double accd = 0.0;
    if (lane < NC) {
        const float* crow = xt + (size_t)b * NN * CC + (size_t)fi * CC;
        const float* qrow = &s_qT[q][0];
        double a0 = 0.0, a1 = 0.0, a2 = 0.0, a3 = 0.0;
#pragma unroll
        for (int j = 0; j < 16; ++j) {
            float4 cv = *(const float4*)(crow + j * 4);
            float4 qv = *(const float4*)(qrow + j * 4);   // LDS b128 broadcast
            a0 = fma((double)qv.x, (double)cv.x, a0);
            a1 = fma((double)qv.y, (double)cv.y, a1);
            a2 = fma((double)qv.z, (double)cv.z, a2);
            a3 = fma((double)qv.w, (double)cv.w, a3);
        }
        accd = (a0 + a1) + (a2 + a3);
    }

    double val = -INFINITY;
    int idxq = 0x7fffffff;
    if (lane < NC) {
        val = 2.0 * accd - xxd[b * NN + nq] - xxd[b * NN + fi];
        idxq = fi;
    }

    // 32-lane fp64 bitonic (val desc, idx asc)
#pragma unroll
    for (int k = 2; k <= 32; k <<= 1) {
#pragma unroll
        for (int j = k >> 1; j > 0; j >>= 1) {
            double ov = __shfl_xor(val, j, 32);
            int oi = __shfl_xor(idxq, j, 32);
            bool dird = ((lane & k) == 0);
            bool first = ((lane & j) == 0);
            bool better = (val > ov) || (val == ov && idxq < oi);
            if (better != (first == dird)) { val = ov; idxq = oi; }
        }
    }

    if (lane < KK) {
        size_t obase = ((size_t)b * NN + nq) * KK;
        idx_ws[obase + lane] = idxq;
        idx_out[obase + lane] = (float)(idxq + b * NN);
    }
}

// ---------------------------------------------------------------------------
// x1: mean of top-14 of 20 gathered neighbor values, written channel-major
// as x1t[b][c][n]. (sum20 - six minima)/14, order-independent.
// ---------------------------------------------------------------------------
__global__ __launch_bounds__(256) void x1_kernel(const float* __restrict__ xt,
                                                 const int* __restrict__ idx_ws,
                                                 float* __restrict__ x1t) {
    __shared__ int s_idx[16][KK];
    __shared__ float s_out[64][17];
    int tid = threadIdx.x;
    int b = blockIdx.x >> 7;
    int n0 = (blockIdx.x & 127) * 16;
    const float* xtb = xt + (size_t)b * NN * CC;

    for (int i = tid; i < 16 * KK; i += 256)
        s_idx[i / KK][i % KK] = idx_ws[((size_t)b * NN + n0) * KK + i];
    __syncthreads();

    int pl = tid >> 6, c = tid & 63;
#pragma unroll
    for (int it = 0; it < 4; ++it) {
        int nl = it * 4 + pl;
        float vals[KK];
        float sum = 0.f;
#pragma unroll
        for (int j = 0; j < KK; ++j) {
            vals[j] = xtb[(size_t)s_idx[nl][j] * CC + c];
            sum += vals[j];
        }
#pragma unroll
        for (int t = 0; t < KK - K2; ++t) {
            float worst = INFINITY;
            int wj = 0;
#pragma unroll
            for (int j = 0; j < KK; ++j)
                if (vals[j] < worst) { worst = vals[j]; wj = j; }
            sum -= worst;
            vals[wj] = INFINITY;
        }
        s_out[c][nl] = sum / (float)K2;
    }
    __syncthreads();

    int cw = tid >> 2, nw = (tid & 3) * 4;
    float4 v = make_float4(s_out[cw][nw], s_out[cw][nw + 1],
                           s_out[cw][nw + 2], s_out[cw][nw + 3]);
    *(float4*)(&x1t[((size_t)b * CC + cw) * NN + n0 + nw]) = v;
}

// ---------------------------------------------------------------------------
// feat: float4-vectorized. feature[b,ch,n,j]:
//   ch <  64: x1t[b,ch,idx[b,n,j]] - x[b,ch,n]
//   ch >= 64: x[b,ch-64,n]
// Write-only 335 MB output -> non-temporal stores.
// ---------------------------------------------------------------------------
__global__ __launch_bounds__(256) void feat_kernel(const float* __restrict__ x,
                                                   const float* __restrict__ x1t,
                                                   const int* __restrict__ idx_ws,
                                                   float* __restrict__ out) {
    int bc = blockIdx.x;
    int b = bc >> 7, ch = bc & 127;
    const float* xb = x + (size_t)b * CC * NN;
    float* o = out + (size_t)bc * NN * KK;
    const int* idxb = idx_ws + (size_t)b * NN * KK;

    if (ch < CC) {
        const float* row = x1t + ((size_t)b * CC + ch) * NN;
        const float* xr = xb + ch * NN;
        for (int it = 0; it < 40; ++it) {
            unsigned e = (it * 256 + threadIdx.x) * 4;
            int4 id4 = *(const int4*)(idxb + e);
            nfloat4 o4;
            o4.x = row[id4.x] - xr[(e    ) / KK];
            o4.y = row[id4.y] - xr[(e + 1) / KK];
            o4.z = row[id4.z] - xr[(e + 2) / KK];
            o4.w = row[id4.w] - xr[(e + 3) / KK];
            __builtin_nontemporal_store(o4, (nfloat4*)(o + e));
        }
    } else {
        const float* xr = xb + (ch - CC) * NN;
        for (int it = 0; it < 40; ++it) {
            unsigned e = (it * 256 + threadIdx.x) * 4;
            nfloat4 o4;
            o4.x = xr[(e    ) / KK];
            o4.y = xr[(e + 1) / KK];
            o4.z = xr[(e + 2) / KK];
            o4.w = xr[(e + 3) / KK];
            __builtin_nontemporal_store(o4, (nfloat4*)(o + e));
        }
    }
}

// ---------------------------------------------------------------------------
extern "C" void kernel_launch(void* const* d_in, const int* in_sizes, int n_in,
                              void* d_out, int out_size, void* d_ws, size_t ws_size,
                              hipStream_t stream) {
    const float* x = (const float*)d_in[0];   // (B, C, N) fp32
    float* out = (float*)d_out;

    char* ws = (char*)d_ws;
    float* xt   = (float*)ws;                                   // B*N*C
    float* x1t  = (float*)(ws + (size_t)8388608);               // B*C*N
    double* xxd = (double*)(ws + (size_t)16777216);             // B*N
    float* xxf  = (float*)(ws + (size_t)17039360);              // B*N
    int* idx_ws = (int*)(ws + (size_t)17170432);                // B*N*K

    float* idx_out = out + (size_t)BB * 2 * CC * NN * KK;       // idx_flat tail

    prep_kernel<<<BB * (NN / 64), 256, 0, stream>>>(x, xt, xxf, xxd);
    knn_kernel<<<BB * (NN / TQ), 512, 0, stream>>>(x, xt, xxf, xxd, idx_ws, idx_out);
    x1_kernel<<<BB * (NN / 16), 256, 0, stream>>>(xt, idx_ws, x1t);
    feat_kernel<<<BB * 2 * CC, 256, 0, stream>>>(x, x1t, idx_ws, out);
}

// Round 9
// 578.224 us; speedup vs baseline: 1.0442x; 1.0028x over previous
//
#include <hip/hip_runtime.h>
#include <hip/hip_fp16.h>
#include <cstdint>
#include <cstddef>
#include <math.h>

// Problem constants (match reference: B,C,N,K = 16,64,2048,20)
#define BB 16
#define CC 64
#define NN 2048
#define KK 20
#define K2 14   // ceil(20*2/3)
#define TQ 16   // queries per block in knn kernel (one per wave, 16 waves)
#define NC 26   // candidate count (margin over K=20 for approx->fp64 rank safety)
#define SPH 2052 // fp16 pd row stride (halves)

// native clang vector type for nontemporal builtin (HIP float4 is a class)
typedef float nfloat4 __attribute__((ext_vector_type(4)));

// ---------------------------------------------------------------------------
// prep: xt[b][n][c] = x[b][c][n]  (fp32, 256B rows), plus norms in fp64+fp32.
// ---------------------------------------------------------------------------
__global__ __launch_bounds__(256) void prep_kernel(const float* __restrict__ x,
                                                   float* __restrict__ xt,
                                                   float* __restrict__ xxf,
                                                   double* __restrict__ xxd) {
    __shared__ float s_t[64][65];
    int b = blockIdx.x >> 5;
    int n0 = (blockIdx.x & 31) * 64;
    const float* xb = x + (size_t)b * CC * NN;
    int tid = threadIdx.x;
    int cq = tid >> 6;
    int nl = tid & 63;

#pragma unroll
    for (int r = 0; r < 16; ++r) {
        int c = r * 4 + cq;
        s_t[c][nl] = xb[c * NN + n0 + nl];
    }
    __syncthreads();

#pragma unroll
    for (int r = 0; r < 16; ++r) {
        int n = r * 4 + cq;
        xt[((size_t)b * NN + n0 + n) * CC + nl] = s_t[nl][n];
    }

    if (tid < 64) {
        double s = 0.0;
#pragma unroll
        for (int c = 0; c < CC; ++c) {
            double v = (double)s_t[c][tid];
            s += v * v;
        }
        xxd[b * NN + n0 + tid] = s;
        xxf[b * NN + n0 + tid] = (float)s;
    }
}

// ---------------------------------------------------------------------------
// knn v10: TQ=16, 1024 threads = 16 waves (one query per wave). Halves the
// per-batch x panel re-reads vs TQ=8 (128 blocks x 512KB instead of 256 x
// 512KB => ~30us less L2 traffic chip-wide), which round-8 decomposition
// identified as the largest fill component. Each thread owns 2 points
// (float2 x loads); q stays on the scalar path (wave-uniform address).
// LDS ~78KB -> 2 blocks/CU = 32 waves/CU (full occupancy).
// Phases 2/3 are per-wave and byte-identical to v9's logic.
// ---------------------------------------------------------------------------
__global__ __launch_bounds__(1024, 8) void knn_kernel(const float* __restrict__ x,
                                                      const float* __restrict__ xt,
                                                      const float* __restrict__ xxf,
                                                      const double* __restrict__ xxd,
                                                      int* __restrict__ idx_ws,
                                                      float* __restrict__ idx_out) {
    __shared__ __half s_pd[TQ][SPH];               // 65.7 KiB fp16 pd rows
    __shared__ __align__(16) float s_qT[TQ][CC];   // 4 KiB, [q][c] for phase 3
    __shared__ float s_sv[TQ][64];                 // survivor values (4 KiB)
    __shared__ int   s_si[TQ][64];                 // survivor indices (4 KiB)

    int tid = threadIdx.x;
    int b = blockIdx.x >> 7;                       // NN/TQ = 128 blocks/batch
    int n0 = (blockIdx.x & 127) * TQ;
    const float* xb = x + (size_t)b * CC * NN;

    {
        int c = tid >> 4, qq = tid & 15;
        s_qT[qq][c] = xb[c * NN + n0 + qq];
    }
    __syncthreads();

    // ---- phase 1: fill (thread owns 2 consecutive m for all 16 queries) ----
    {
        float xxn[TQ];
#pragma unroll
        for (int i = 0; i < TQ; i += 4) {
            float4 t = *(const float4*)(xxf + b * NN + n0 + i);   // uniform -> s_load
            xxn[i] = t.x; xxn[i + 1] = t.y; xxn[i + 2] = t.z; xxn[i + 3] = t.w;
        }

        int m = tid * 2;
        float acc[TQ][2];
#pragma unroll
        for (int q = 0; q < TQ; ++q) { acc[q][0] = 0.f; acc[q][1] = 0.f; }

        for (int c = 0; c < CC; ++c) {
            float2 xv = *(const float2*)(xb + c * NN + m);
            // wave-uniform address -> scalar loads (constant cache, no LDS)
            const float* qp = xb + c * NN + n0;
            float qs[TQ];
#pragma unroll
            for (int i = 0; i < TQ; i += 4) {
                float4 t = *(const float4*)(qp + i);
                qs[i] = t.x; qs[i + 1] = t.y; qs[i + 2] = t.z; qs[i + 3] = t.w;
            }
#pragma unroll
            for (int q = 0; q < TQ; ++q) {
                acc[q][0] += qs[q] * xv.x;
                acc[q][1] += qs[q] * xv.y;
            }
        }
        float2 xm2 = *(const float2*)(xxf + b * NN + m);
#pragma unroll
        for (int q = 0; q < TQ; ++q) {
            float p0 = (2.f * acc[q][0] - xxn[q]) - xm2.x;
            float p1 = (2.f * acc[q][1] - xxn[q]) - xm2.y;
            *(__half2*)(&s_pd[q][m]) = __floats2half2_rn(p0, p1);
        }
    }
    __syncthreads();

    // ---- phase 2: per-wave selection ----
    int q = tid >> 6;
    int lane = tid & 63;
    const __half* pd = &s_pd[q][0];

    float v[32];
#pragma unroll
    for (int r = 0; r < 32; ++r) v[r] = __half2float(pd[lane + (r << 6)]);

    float lmax = v[0]; int lr = 0;
#pragma unroll
    for (int r = 1; r < 32; ++r)
        if (v[r] > lmax) { lmax = v[r]; lr = r; }              // strict > : lowest idx

    // tau = 26th-largest lane-max (values-only 64-lane bitonic, descending)
    float sv = lmax;
#pragma unroll
    for (int k = 2; k <= 64; k <<= 1) {
#pragma unroll
        for (int j = k >> 1; j > 0; j >>= 1) {
            float o = __shfl_xor(sv, j);
            bool dird = ((lane & k) == 0);
            bool first = ((lane & j) == 0);
            sv = (first == dird) ? fmaxf(sv, o) : fminf(sv, o);
        }
    }
    float tau = __shfl(sv, 25);

    int cnt = 0;
#pragma unroll
    for (int r = 0; r < 32; ++r) cnt += (v[r] >= tau) ? 1 : 0;
    int incl = cnt;
#pragma unroll
    for (int off = 1; off < 64; off <<= 1) {
        int o = __shfl_up(incl, off);
        if (lane >= off) incl += o;
    }
    int S = __shfl(incl, 63);

    float fv = -INFINITY;
    int fi = 0x7fffffff;
    if (S <= 64) {
        int w = incl - cnt;
#pragma unroll
        for (int r = 0; r < 32; ++r) {
            if (v[r] >= tau) { s_sv[q][w] = v[r]; s_si[q][w] = lane + (r << 6); ++w; }
        }
        if (lane < S) { fv = s_sv[q][lane]; fi = s_si[q][lane]; }
    } else {
        // pathological (mass ties): exact iterative top-26 extraction
        for (int t = 0; t < NC; ++t) {
            float bv = lmax; int bi = lane + (lr << 6);
#pragma unroll
            for (int off = 32; off; off >>= 1) {
                float ov = __shfl_xor(bv, off);
                int oi = __shfl_xor(bi, off);
                if (ov > bv || (ov == bv && oi < bi)) { bv = ov; bi = oi; }
            }
            if (lane == t) { fv = bv; fi = bi; }
            if ((bi & 63) == lane) {
                int rsel = bi >> 6;
#pragma unroll
                for (int r = 0; r < 32; ++r) if (r == rsel) v[r] = -INFINITY;
                lmax = v[0]; lr = 0;
#pragma unroll
                for (int r = 1; r < 32; ++r)
                    if (v[r] > lmax) { lmax = v[r]; lr = r; }
            }
        }
    }

    // 64-lane bitonic sort of (fv desc, fi asc) -> lanes 0..25 = approx top-26
#pragma unroll
    for (int k = 2; k <= 64; k <<= 1) {
#pragma unroll
        for (int j = k >> 1; j > 0; j >>= 1) {
            float ov = __shfl_xor(fv, j);
            int oi = __shfl_xor(fi, j);
            bool dird = ((lane & k) == 0);
            bool first = ((lane & j) == 0);
            bool better = (fv > ov) || (fv == ov && fi < oi);
            if (better != (first == dird)) { fv = ov; fi = oi; }
        }
    }

    // ---- phase 3: fp64 refine (direct global candidate rows, L2-hot) ----
    int nq = n0 + q;
    double accd = 0.0;
    if (lane < NC) {
        const float* crow = xt + (size_t)b * NN * CC + (size_t)fi * CC;
        const float* qrow = &s_qT[q][0];
        double a0 = 0.0, a1 = 0.0, a2 = 0.0, a3 = 0.0;
#pragma unroll
        for (int j = 0; j < 16; ++j) {
            float4 cv = *(const float4*)(crow + j * 4);
            float4 qv = *(const float4*)(qrow + j * 4);   // LDS b128 broadcast
            a0 = fma((double)qv.x, (double)cv.x, a0);
            a1 = fma((double)qv.y, (double)cv.y, a1);
            a2 = fma((double)qv.z, (double)cv.z, a2);
            a3 = fma((double)qv.w, (double)cv.w, a3);
        }
        accd = (a0 + a1) + (a2 + a3);
    }

    double val = -INFINITY;
    int idxq = 0x7fffffff;
    if (lane < NC) {
        val = 2.0 * accd - xxd[b * NN + nq] - xxd[b * NN + fi];
        idxq = fi;
    }

    // 32-lane fp64 bitonic (val desc, idx asc)
#pragma unroll
    for (int k = 2; k <= 32; k <<= 1) {
#pragma unroll
        for (int j = k >> 1; j > 0; j >>= 1) {
            double ov = __shfl_xor(val, j, 32);
            int oi = __shfl_xor(idxq, j, 32);
            bool dird = ((lane & k) == 0);
            bool first = ((lane & j) == 0);
            bool better = (val > ov) || (val == ov && idxq < oi);
            if (better != (first == dird)) { val = ov; idxq = oi; }
        }
    }

    if (lane < KK) {
        size_t obase = ((size_t)b * NN + nq) * KK;
        idx_ws[obase + lane] = idxq;
        idx_out[obase + lane] = (float)(idxq + b * NN);
    }
}

// ---------------------------------------------------------------------------
// x1: mean of top-14 of 20 gathered neighbor values, written channel-major
// as x1t[b][c][n]. (sum20 - six minima)/14, order-independent.
// ---------------------------------------------------------------------------
__global__ __launch_bounds__(256) void x1_kernel(const float* __restrict__ xt,
                                                 const int* __restrict__ idx_ws,
                                                 float* __restrict__ x1t) {
    __shared__ int s_idx[16][KK];
    __shared__ float s_out[64][17];
    int tid = threadIdx.x;
    int b = blockIdx.x >> 7;
    int n0 = (blockIdx.x & 127) * 16;
    const float* xtb = xt + (size_t)b * NN * CC;

    for (int i = tid; i < 16 * KK; i += 256)
        s_idx[i / KK][i % KK] = idx_ws[((size_t)b * NN + n0) * KK + i];
    __syncthreads();

    int pl = tid >> 6, c = tid & 63;
#pragma unroll
    for (int it = 0; it < 4; ++it) {
        int nl = it * 4 + pl;
        float vals[KK];
        float sum = 0.f;
#pragma unroll
        for (int j = 0; j < KK; ++j) {
            vals[j] = xtb[(size_t)s_idx[nl][j] * CC + c];
            sum += vals[j];
        }
#pragma unroll
        for (int t = 0; t < KK - K2; ++t) {
            float worst = INFINITY;
            int wj = 0;
#pragma unroll
            for (int j = 0; j < KK; ++j)
                if (vals[j] < worst) { worst = vals[j]; wj = j; }
            sum -= worst;
            vals[wj] = INFINITY;
        }
        s_out[c][nl] = sum / (float)K2;
    }
    __syncthreads();

    int cw = tid >> 2, nw = (tid & 3) * 4;
    float4 v = make_float4(s_out[cw][nw], s_out[cw][nw + 1],
                           s_out[cw][nw + 2], s_out[cw][nw + 3]);
    *(float4*)(&x1t[((size_t)b * CC + cw) * NN + n0 + nw]) = v;
}

// ---------------------------------------------------------------------------
// feat: float4-vectorized. feature[b,ch,n,j]:
//   ch <  64: x1t[b,ch,idx[b,n,j]] - x[b,ch,n]
//   ch >= 64: x[b,ch-64,n]
// Write-only 335 MB output -> non-temporal stores.
// ---------------------------------------------------------------------------
__global__ __launch_bounds__(256) void feat_kernel(const float* __restrict__ x,
                                                   const float* __restrict__ x1t,
                                                   const int* __restrict__ idx_ws,
                                                   float* __restrict__ out) {
    int bc = blockIdx.x;
    int b = bc >> 7, ch = bc & 127;
    const float* xb = x + (size_t)b * CC * NN;
    float* o = out + (size_t)bc * NN * KK;
    const int* idxb = idx_ws + (size_t)b * NN * KK;

    if (ch < CC) {
        const float* row = x1t + ((size_t)b * CC + ch) * NN;
        const float* xr = xb + ch * NN;
        for (int it = 0; it < 40; ++it) {
            unsigned e = (it * 256 + threadIdx.x) * 4;
            int4 id4 = *(const int4*)(idxb + e);
            nfloat4 o4;
            o4.x = row[id4.x] - xr[(e    ) / KK];
            o4.y = row[id4.y] - xr[(e + 1) / KK];
            o4.z = row[id4.z] - xr[(e + 2) / KK];
            o4.w = row[id4.w] - xr[(e + 3) / KK];
            __builtin_nontemporal_store(o4, (nfloat4*)(o + e));
        }
    } else {
        const float* xr = xb + (ch - CC) * NN;
        for (int it = 0; it < 40; ++it) {
            unsigned e = (it * 256 + threadIdx.x) * 4;
            nfloat4 o4;
            o4.x = xr[(e    ) / KK];
            o4.y = xr[(e + 1) / KK];
            o4.z = xr[(e + 2) / KK];
            o4.w = xr[(e + 3) / KK];
            __builtin_nontemporal_store(o4, (nfloat4*)(o + e));
        }
    }
}

// ---------------------------------------------------------------------------
extern "C" void kernel_launch(void* const* d_in, const int* in_sizes, int n_in,
                              void* d_out, int out_size, void* d_ws, size_t ws_size,
                              hipStream_t stream) {
    const float* x = (const float*)d_in[0];   // (B, C, N) fp32
    float* out = (float*)d_out;

    char* ws = (char*)d_ws;
    float* xt   = (float*)ws;                                   // B*N*C
    float* x1t  = (float*)(ws + (size_t)8388608);               // B*C*N
    double* xxd = (double*)(ws + (size_t)16777216);             // B*N
    float* xxf  = (float*)(ws + (size_t)17039360);              // B*N
    int* idx_ws = (int*)(ws + (size_t)17170432);                // B*N*K

    float* idx_out = out + (size_t)BB * 2 * CC * NN * KK;       // idx_flat tail

    prep_kernel<<<BB * (NN / 64), 256, 0, stream>>>(x, xt, xxf, xxd);
    knn_kernel<<<BB * (NN / TQ), 1024, 0, stream>>>(x, xt, xxf, xxd, idx_ws, idx_out);
    x1_kernel<<<BB * (NN / 16), 256, 0, stream>>>(xt, idx_ws, x1t);
    feat_kernel<<<BB * 2 * CC, 256, 0, stream>>>(x, x1t, idx_ws, out);
}